// Round 3
// baseline (583.944 us; speedup 1.0000x reference)
//
#include <hip/hip_runtime.h>

typedef _Float16 f16;
typedef f16 f16x8 __attribute__((ext_vector_type(8)));
typedef float f32x4 __attribute__((ext_vector_type(4)));

#define NROWS 16384
#define KDIM  1024
#define IDIM  256
#define ODIM  512

// ---- workspace layout (bytes) ----
#define WS_LOGITS 0
#define WS_WT_ATT 262144
#define WS_WT_TR  1835008

__device__ __forceinline__ float fast_tanhf(float x) {
    float ax = fabsf(x);
    float e = __expf(-2.0f * ax);          // in (0,1], overflow-safe
    float t = (1.0f - e) / (1.0f + e);
    return copysignf(t, x);
}

// pack 8 fp32 -> f16x8 (RNE via scalar cvt, same numerics as round-2 PASS)
__device__ __forceinline__ f16x8 cvt8(float4 a, float4 b) {
    f16x8 r;
    r[0] = (f16)a.x; r[1] = (f16)a.y; r[2] = (f16)a.z; r[3] = (f16)a.w;
    r[4] = (f16)b.x; r[5] = (f16)b.y; r[6] = (f16)b.z; r[7] = (f16)b.w;
    return r;
}
// scale in fp32 THEN convert (identical rounding structure to round-2 PASS)
__device__ __forceinline__ f16x8 cvt8s(float4 a, float4 b, float s) {
    f16x8 r;
    r[0] = (f16)(a.x * s); r[1] = (f16)(a.y * s); r[2] = (f16)(a.z * s); r[3] = (f16)(a.w * s);
    r[4] = (f16)(b.x * s); r[5] = (f16)(b.y * s); r[6] = (f16)(b.z * s); r[7] = (f16)(b.w * s);
    return r;
}

// ---------------------------------------------------------------------------
// Kernel 0: transpose + f16-convert the six weight matrices: W[K][N] -> WT[N][K]
// ---------------------------------------------------------------------------
__global__ __launch_bounds__(256) void transpose_w_kernel(
    const float* __restrict__ Wa0, const float* __restrict__ Wa1, const float* __restrict__ Wa2,
    const float* __restrict__ Wt0, const float* __restrict__ Wt1, const float* __restrict__ Wt2,
    f16* __restrict__ wta, f16* __restrict__ wtt)
{
    __shared__ float tile[64][65];
    int mat = blockIdx.y;  // 0..2 att, 3..5 tr
    const float* src;
    f16* dst;
    int N;
    if (mat < 3) {
        src = (mat == 0) ? Wa0 : (mat == 1) ? Wa1 : Wa2;
        dst = wta + (size_t)mat * IDIM * KDIM;
        N = IDIM;
    } else {
        int m = mat - 3;
        src = (m == 0) ? Wt0 : (m == 1) ? Wt1 : Wt2;
        dst = wtt + (size_t)m * ODIM * KDIM;
        N = ODIM;
    }
    int ntiles = (N / 64) * (KDIM / 64);
    int tilei = blockIdx.x;
    if (tilei >= ntiles) return;  // uniform per block
    int tn = tilei / (KDIM / 64);
    int tk = tilei % (KDIM / 64);
    int n0 = tn * 64, k0 = tk * 64;
    int t = threadIdx.x;

    #pragma unroll
    for (int j = 0; j < 16; ++j) {
        int f = j * 256 + t;
        int r = f >> 6, c = f & 63;
        tile[r][c] = src[(size_t)(k0 + r) * N + n0 + c];
    }
    __syncthreads();
    #pragma unroll
    for (int j = 0; j < 8; ++j) {
        int p = j * 256 + t;
        int n = p >> 5, kp = p & 31;
        union { f16 h[2]; unsigned int u; } pk;
        pk.h[0] = (f16)tile[2 * kp][n];
        pk.h[1] = (f16)tile[2 * kp + 1][n];
        *(unsigned int*)(&dst[(size_t)(n0 + n) * KDIM + k0 + 2 * kp]) = pk.u;
    }
}

// ---------------------------------------------------------------------------
// Kernel 1: logits[b, br] = tanh(x_br @ W_att_br + b_att_br) @ v
// Barrier-free: MFMA fragments loaded DIRECTLY from global.
//  - A (x rows): 64-row tile -> 8KB/K-step, L1-resident across the 4 waves.
//  - B (WT_att): 512KB/branch, L2-resident chip-wide.
// One block = 64 rows x one branch; 4 waves; wave w owns cols w*64..w*64+63.
// ---------------------------------------------------------------------------
__global__ __launch_bounds__(256) void logits_kernel(
    const float* __restrict__ x0, const float* __restrict__ x1, const float* __restrict__ x2,
    const float* __restrict__ ba0, const float* __restrict__ ba1, const float* __restrict__ ba2,
    const f16* __restrict__ wta, const float* __restrict__ v,
    float* __restrict__ logits)
{
    __shared__ float red[4][64];

    int br = blockIdx.y;
    const float* x  = (br == 0) ? x0 : (br == 1) ? x1 : x2;
    const float* ba = (br == 0) ? ba0 : (br == 1) ? ba1 : ba2;
    const f16* WT = wta + (size_t)br * IDIM * KDIM;
    int m0 = blockIdx.x * 64;
    int t = threadIdx.x;
    int l = t & 63;
    int w = t >> 6;
    const int row_l = l & 15;        // fragment row within 16
    const int koff  = (l >> 4) * 8;  // lane k-subchunk (8 elems)

    f32x4 acc[4][4];
    #pragma unroll
    for (int i = 0; i < 4; ++i)
        #pragma unroll
        for (int j = 0; j < 4; ++j) acc[i][j] = (f32x4)0.0f;

    const float* xp[4];
    const f16*   bp[4];
    #pragma unroll
    for (int fm = 0; fm < 4; ++fm)
        xp[fm] = x + (size_t)(m0 + fm * 16 + row_l) * KDIM + koff;
    #pragma unroll
    for (int fn = 0; fn < 4; ++fn)
        bp[fn] = WT + (size_t)(w * 64 + fn * 16 + row_l) * KDIM + koff;

    for (int kt = 0; kt < KDIM / 64; ++kt) {
        int k0 = kt * 64;
        f16x8 af[4][2], bf[4][2];
        #pragma unroll
        for (int fm = 0; fm < 4; ++fm)
            #pragma unroll
            for (int kk = 0; kk < 2; ++kk) {
                float4 a = *(const float4*)(xp[fm] + k0 + kk * 32);
                float4 b = *(const float4*)(xp[fm] + k0 + kk * 32 + 4);
                af[fm][kk] = cvt8(a, b);
            }
        #pragma unroll
        for (int fn = 0; fn < 4; ++fn)
            #pragma unroll
            for (int kk = 0; kk < 2; ++kk)
                bf[fn][kk] = *(const f16x8*)(bp[fn] + k0 + kk * 32);
        #pragma unroll
        for (int kk = 0; kk < 2; ++kk)
            #pragma unroll
            for (int fm = 0; fm < 4; ++fm)
                #pragma unroll
                for (int fn = 0; fn < 4; ++fn)
                    acc[fm][fn] = __builtin_amdgcn_mfma_f32_16x16x32_f16(
                        af[fm][kk], bf[fn][kk], acc[fm][fn], 0, 0, 0);
    }

    // ---- epilogue: tanh(acc + b_att) . v, reduce over 256 cols ----
    float vv[4], bb[4];
    #pragma unroll
    for (int fn = 0; fn < 4; ++fn) {
        int col = w * 64 + fn * 16 + (l & 15);
        vv[fn] = v[col];
        bb[fn] = ba[col];
    }
    #pragma unroll
    for (int fm = 0; fm < 4; ++fm) {
        #pragma unroll
        for (int reg = 0; reg < 4; ++reg) {
            float s = 0.f;
            #pragma unroll
            for (int fn = 0; fn < 4; ++fn)
                s += fast_tanhf(acc[fm][fn][reg] + bb[fn]) * vv[fn];
            #pragma unroll
            for (int d = 1; d < 16; d <<= 1)
                s += __shfl_xor(s, d, 64);
            if ((l & 15) == 0) {
                int row = fm * 16 + (l >> 4) * 4 + reg;
                red[w][row] = s;
            }
        }
    }
    __syncthreads();
    if (t < 64) {
        float lg = red[0][t] + red[1][t] + red[2][t] + red[3][t];
        logits[(size_t)(m0 + t) * 3 + br] = lg;
    }
}

// ---------------------------------------------------------------------------
// Kernel 2: out = sum_i soft[:,i] * (x_i @ W_tr_i + b_tr_i)
// Barrier-free direct-fragment version. Softmax weight folded into A convert
// (fp32 mul -> f16, identical numerics to the round-2 PASS).
// Grid (n=2 fast, m=256); m REVERSED so out's x-reads hit the L3 lines the
// logits pass touched last (LIFO reuse; x total 201MB vs 256MB L3).
// ---------------------------------------------------------------------------
__global__ __launch_bounds__(256) void out_kernel(
    const float* __restrict__ x0, const float* __restrict__ x1, const float* __restrict__ x2,
    const float* __restrict__ bt0, const float* __restrict__ bt1, const float* __restrict__ bt2,
    const f16* __restrict__ wtt, const float* __restrict__ logits,
    float* __restrict__ out)
{
    __shared__ float sS[64][4];

    int m0 = (NROWS / 64 - 1 - (int)blockIdx.y) * 64;
    int n0 = blockIdx.x * 256;
    int t = threadIdx.x;
    int l = t & 63;
    int w = t >> 6;
    const int row_l = l & 15;
    const int koff  = (l >> 4) * 8;

    if (t < 64) {
        float l0 = logits[(size_t)(m0 + t) * 3 + 0];
        float l1 = logits[(size_t)(m0 + t) * 3 + 1];
        float l2 = logits[(size_t)(m0 + t) * 3 + 2];
        float mx = fmaxf(l0, fmaxf(l1, l2));
        float e0 = __expf(l0 - mx), e1 = __expf(l1 - mx), e2 = __expf(l2 - mx);
        float inv = 1.0f / (e0 + e1 + e2);
        sS[t][0] = e0 * inv; sS[t][1] = e1 * inv; sS[t][2] = e2 * inv;
    }
    __syncthreads();

    f32x4 acc[4][4];
    #pragma unroll
    for (int i = 0; i < 4; ++i)
        #pragma unroll
        for (int j = 0; j < 4; ++j) acc[i][j] = (f32x4)0.0f;

    for (int brn = 0; brn < 3; ++brn) {
        const float* x = (brn == 0) ? x0 : (brn == 1) ? x1 : x2;
        const f16* WT = wtt + (size_t)brn * ODIM * KDIM;
        float sreg[4];
        #pragma unroll
        for (int fm = 0; fm < 4; ++fm) sreg[fm] = sS[fm * 16 + row_l][brn];

        const float* xp[4];
        const f16*   bp[4];
        #pragma unroll
        for (int fm = 0; fm < 4; ++fm)
            xp[fm] = x + (size_t)(m0 + fm * 16 + row_l) * KDIM + koff;
        #pragma unroll
        for (int fn = 0; fn < 4; ++fn)
            bp[fn] = WT + (size_t)(n0 + w * 64 + fn * 16 + row_l) * KDIM + koff;

        for (int kt = 0; kt < KDIM / 64; ++kt) {
            int k0 = kt * 64;
            f16x8 af[4][2], bf[4][2];
            #pragma unroll
            for (int fm = 0; fm < 4; ++fm)
                #pragma unroll
                for (int kk = 0; kk < 2; ++kk) {
                    float4 a = *(const float4*)(xp[fm] + k0 + kk * 32);
                    float4 b = *(const float4*)(xp[fm] + k0 + kk * 32 + 4);
                    af[fm][kk] = cvt8s(a, b, sreg[fm]);
                }
            #pragma unroll
            for (int fn = 0; fn < 4; ++fn)
                #pragma unroll
                for (int kk = 0; kk < 2; ++kk)
                    bf[fn][kk] = *(const f16x8*)(bp[fn] + k0 + kk * 32);
            #pragma unroll
            for (int kk = 0; kk < 2; ++kk)
                #pragma unroll
                for (int fm = 0; fm < 4; ++fm)
                    #pragma unroll
                    for (int fn = 0; fn < 4; ++fn)
                        acc[fm][fn] = __builtin_amdgcn_mfma_f32_16x16x32_f16(
                            af[fm][kk], bf[fn][kk], acc[fm][fn], 0, 0, 0);
        }
    }

    // ---- epilogue: + sum_i s_i * b_tr_i, fp32 store ----
    float btc[3][4];
    #pragma unroll
    for (int fn = 0; fn < 4; ++fn) {
        int col = n0 + w * 64 + fn * 16 + (l & 15);
        btc[0][fn] = bt0[col];
        btc[1][fn] = bt1[col];
        btc[2][fn] = bt2[col];
    }
    #pragma unroll
    for (int fm = 0; fm < 4; ++fm) {
        #pragma unroll
        for (int reg = 0; reg < 4; ++reg) {
            int row = fm * 16 + (l >> 4) * 4 + reg;
            float s0 = sS[row][0], s1 = sS[row][1], s2 = sS[row][2];
            #pragma unroll
            for (int fn = 0; fn < 4; ++fn) {
                int col = n0 + w * 64 + fn * 16 + (l & 15);
                float val = acc[fm][fn][reg]
                          + s0 * btc[0][fn] + s1 * btc[1][fn] + s2 * btc[2][fn];
                out[(size_t)(m0 + row) * ODIM + col] = val;
            }
        }
    }
}

// ---------------------------------------------------------------------------
extern "C" void kernel_launch(void* const* d_in, const int* in_sizes, int n_in,
                              void* d_out, int out_size, void* d_ws, size_t ws_size,
                              hipStream_t stream)
{
    (void)in_sizes; (void)n_in; (void)out_size; (void)ws_size;
    const float* x0  = (const float*)d_in[0];
    const float* Wa0 = (const float*)d_in[1];
    const float* ba0 = (const float*)d_in[2];
    const float* Wt0 = (const float*)d_in[3];
    const float* bt0 = (const float*)d_in[4];
    const float* x1  = (const float*)d_in[5];
    const float* Wa1 = (const float*)d_in[6];
    const float* ba1 = (const float*)d_in[7];
    const float* Wt1 = (const float*)d_in[8];
    const float* bt1 = (const float*)d_in[9];
    const float* x2  = (const float*)d_in[10];
    const float* Wa2 = (const float*)d_in[11];
    const float* ba2 = (const float*)d_in[12];
    const float* Wt2 = (const float*)d_in[13];
    const float* bt2 = (const float*)d_in[14];
    const float* v   = (const float*)d_in[15];

    char* ws = (char*)d_ws;
    float* logits = (float*)(ws + WS_LOGITS);
    f16* wta = (f16*)(ws + WS_WT_ATT);
    f16* wtt = (f16*)(ws + WS_WT_TR);
    float* out = (float*)d_out;

    transpose_w_kernel<<<dim3(128, 6), 256, 0, stream>>>(Wa0, Wa1, Wa2, Wt0, Wt1, Wt2, wta, wtt);
    logits_kernel<<<dim3(NROWS / 64, 3), 256, 0, stream>>>(x0, x1, x2, ba0, ba1, ba2, wta, v, logits);
    out_kernel<<<dim3(2, NROWS / 64), 256, 0, stream>>>(x0, x1, x2, bt0, bt1, bt2, wtt, logits, out);
}

// Round 5
// 405.727 us; speedup vs baseline: 1.4393x; 1.4393x over previous
//
#include <hip/hip_runtime.h>

typedef _Float16 f16;
typedef f16 f16x8 __attribute__((ext_vector_type(8)));
typedef f16 f16x4 __attribute__((ext_vector_type(4)));
typedef float f32x4 __attribute__((ext_vector_type(4)));
typedef unsigned int u32;

#define NROWS 16384
#define KDIM  1024
#define IDIM  256
#define ODIM  512

// ---- workspace layout (bytes) ----
#define WS_LOGITS 0
#define WS_WT_ATT 262144
#define WS_WT_TR  1835008

__device__ __forceinline__ float fast_tanhf(float x) {
    float ax = fabsf(x);
    float e = __expf(-2.0f * ax);
    float t = (1.0f - e) / (1.0f + e);
    return copysignf(t, x);
}

__device__ __forceinline__ const float* sel3(int i, const float* a, const float* b, const float* c) {
    return i == 0 ? a : (i == 1 ? b : c);
}

// async 16B/lane global->LDS copy; lds_base wave-uniform, g per-lane (G21 pattern)
__device__ __forceinline__ void gld16(char* lds_base, const char* g, int lane) {
#if __has_builtin(__builtin_amdgcn_global_load_lds)
    __builtin_amdgcn_global_load_lds((const __attribute__((address_space(1))) u32*)g,
                                     (__attribute__((address_space(3))) u32*)lds_base, 16, 0, 0);
#else
    *(f16x8*)(lds_base + lane * 16) = *(const f16x8*)g;
#endif
}

// swizzled LDS byte addr: 128B rows (out) and 64B rows w/ superrow pairing (logits)
__device__ __forceinline__ int swz128(int row, int c) { return (row * 128 + c) ^ ((row & 7) << 4); }
__device__ __forceinline__ int swz64 (int row, int c) { return (row * 64 + c) ^ (((row >> 1) & 7) << 4); }

// ---------------------------------------------------------------------------
// Kernel 0: transpose + f16-convert weights: W[K][N] -> WT[N][K]
// ---------------------------------------------------------------------------
__global__ __launch_bounds__(256) void transpose_w_kernel(
    const float* __restrict__ Wa0, const float* __restrict__ Wa1, const float* __restrict__ Wa2,
    const float* __restrict__ Wt0, const float* __restrict__ Wt1, const float* __restrict__ Wt2,
    f16* __restrict__ wta, f16* __restrict__ wtt)
{
    __shared__ float tile[64][65];
    int mat = blockIdx.y;
    const float* src;
    f16* dst;
    int N;
    if (mat < 3) {
        src = (mat == 0) ? Wa0 : (mat == 1) ? Wa1 : Wa2;
        dst = wta + (size_t)mat * IDIM * KDIM;
        N = IDIM;
    } else {
        int m = mat - 3;
        src = (m == 0) ? Wt0 : (m == 1) ? Wt1 : Wt2;
        dst = wtt + (size_t)m * ODIM * KDIM;
        N = ODIM;
    }
    int ntiles = (N / 64) * (KDIM / 64);
    int tilei = blockIdx.x;
    if (tilei >= ntiles) return;
    int tn = tilei / (KDIM / 64);
    int tk = tilei % (KDIM / 64);
    int n0 = tn * 64, k0 = tk * 64;
    int t = threadIdx.x;

    #pragma unroll
    for (int j = 0; j < 16; ++j) {
        int f = j * 256 + t;
        int r = f >> 6, c = f & 63;
        tile[r][c] = src[(size_t)(k0 + r) * N + n0 + c];
    }
    __syncthreads();
    #pragma unroll
    for (int j = 0; j < 8; ++j) {
        int p = j * 256 + t;
        int n = p >> 5, kp = p & 31;
        union { f16 h[2]; unsigned int u; } pk;
        pk.h[0] = (f16)tile[2 * kp][n];
        pk.h[1] = (f16)tile[2 * kp + 1][n];
        *(unsigned int*)(&dst[(size_t)(n0 + n) * KDIM + k0 + 2 * kp]) = pk.u;
    }
}

// ---------------------------------------------------------------------------
// Kernel 1: logits[b,br] = tanh(x_br @ W_att_br + b_att_br) @ v
// BM=64, BN=256(full), BK=32, 512 threads (8 waves, 2M x 4N, wave 32x64).
// T3-minimum pipeline: 1 barrier/iter, dbuf; B via global_load_lds with
// pre-swizzled source; A reg-staged (fp32->f16 cvt).
// ---------------------------------------------------------------------------
__global__ __launch_bounds__(512, 4) void logits_kernel(
    const float* __restrict__ x0, const float* __restrict__ x1, const float* __restrict__ x2,
    const float* __restrict__ ba0, const float* __restrict__ ba1, const float* __restrict__ ba2,
    const f16* __restrict__ wta, const float* __restrict__ v,
    float* __restrict__ logits)
{
    __shared__ __align__(16) char sA[2][4096];    // 64 rows x 32 f16 (swz64)
    __shared__ __align__(16) char sB[2][16384];   // 256 rows x 32 f16 (swz64 via source)

    int br = blockIdx.y;
    const float* x  = sel3(br, x0, x1, x2);
    const float* ba = sel3(br, ba0, ba1, ba2);
    const f16* WT = wta + (size_t)br * IDIM * KDIM;
    int m0 = blockIdx.x * 64;
    int t = threadIdx.x;
    int l = t & 63;
    int w = t >> 6;          // 0..7
    int wm = w >> 2;         // 0..1
    int wn = w & 3;          // 0..3
    int fr = l & 15;
    int ch = l >> 4;         // 0..3

    // A staging: thread t covers row=t>>3, float4 seg=t&7 (8B f16 out)
    int s_row = t >> 3;
    int s_seg = t & 7;
    const float* xrow = x + (size_t)(m0 + s_row) * KDIM + s_seg * 4;
    int aw_addr = swz64(s_row, s_seg * 8);

    // B gld: 2 instrs/wave, each covers 16 rows x 64B = 1KB
    int gdst[2], gsrow[2], gsc[2];
    #pragma unroll
    for (int j = 0; j < 2; ++j) {
        int nbase = w * 32 + j * 16;
        int o = nbase * 64 + l * 16;
        int sup = o >> 7, within = o & 127;
        int u = within ^ ((sup & 7) << 4);
        gdst[j] = nbase * 64;
        gsrow[j] = sup * 2 + (u >> 6);
        gsc[j] = u & 63;
    }

    // fragment read offsets (within a buffer)
    int aoff[2], boff[4];
    #pragma unroll
    for (int fm = 0; fm < 2; ++fm) {
        int row = wm * 32 + fm * 16 + fr;
        aoff[fm] = swz64(row, ch * 16);
    }
    #pragma unroll
    for (int fn = 0; fn < 4; ++fn) {
        int n = wn * 64 + fn * 16 + fr;
        boff[fn] = swz64(n, ch * 16);
    }

    f32x4 acc[2][4];
    #pragma unroll
    for (int i = 0; i < 2; ++i)
        #pragma unroll
        for (int j = 0; j < 4; ++j) acc[i][j] = (f32x4)0.0f;

    // prologue: stage kt=0 into buf 0
    {
        float4 av = *(const float4*)(xrow);
        f16x4 hv;
        hv[0] = (f16)av.x; hv[1] = (f16)av.y; hv[2] = (f16)av.z; hv[3] = (f16)av.w;
        *(f16x4*)(sA[0] + aw_addr) = hv;
        #pragma unroll
        for (int j = 0; j < 2; ++j)
            gld16(sB[0] + gdst[j], (const char*)WT + (size_t)gsrow[j] * 2048 + gsc[j], l);
    }
    __syncthreads();

    int buf = 0;
    for (int kt = 0; kt < 32; ++kt) {
        bool has = (kt + 1) < 32;
        float4 av;
        if (has) {
            int k0 = (kt + 1) * 32;
            av = *(const float4*)(xrow + k0);
            #pragma unroll
            for (int j = 0; j < 2; ++j)
                gld16(sB[buf ^ 1] + gdst[j],
                      (const char*)WT + (size_t)gsrow[j] * 2048 + (size_t)k0 * 2 + gsc[j], l);
        }
        // compute on buf
        f16x8 af[2], bf[4];
        #pragma unroll
        for (int fm = 0; fm < 2; ++fm) af[fm] = *(const f16x8*)(sA[buf] + aoff[fm]);
        #pragma unroll
        for (int fn = 0; fn < 4; ++fn) bf[fn] = *(const f16x8*)(sB[buf] + boff[fn]);
        #pragma unroll
        for (int fm = 0; fm < 2; ++fm)
            #pragma unroll
            for (int fn = 0; fn < 4; ++fn)
                acc[fm][fn] = __builtin_amdgcn_mfma_f32_16x16x32_f16(af[fm], bf[fn], acc[fm][fn], 0, 0, 0);
        if (has) {
            f16x4 hv;
            hv[0] = (f16)av.x; hv[1] = (f16)av.y; hv[2] = (f16)av.z; hv[3] = (f16)av.w;
            *(f16x4*)(sA[buf ^ 1] + aw_addr) = hv;
        }
        __syncthreads();
        buf ^= 1;
    }

    // ---- epilogue: tanh(acc + b_att) . v, reduce over 256 cols ----
    float* red = (float*)sA;  // [4][64] overlay (sA dead after loop)
    float vv[4], bb[4];
    #pragma unroll
    for (int fn = 0; fn < 4; ++fn) {
        int col = wn * 64 + fn * 16 + fr;
        vv[fn] = v[col];
        bb[fn] = ba[col];
    }
    #pragma unroll
    for (int fm = 0; fm < 2; ++fm) {
        #pragma unroll
        for (int reg = 0; reg < 4; ++reg) {
            float s = 0.f;
            #pragma unroll
            for (int fn = 0; fn < 4; ++fn)
                s += fast_tanhf(acc[fm][fn][reg] + bb[fn]) * vv[fn];
            #pragma unroll
            for (int d = 1; d < 16; d <<= 1)
                s += __shfl_xor(s, d, 64);
            if (fr == 0) {
                int row = wm * 32 + fm * 16 + ch * 4 + reg;
                red[wn * 64 + row] = s;
            }
        }
    }
    __syncthreads();
    if (t < 64) {
        float lg = red[t] + red[64 + t] + red[128 + t] + red[192 + t];
        logits[(size_t)(m0 + t) * 3 + br] = lg;
    }
}

// ---------------------------------------------------------------------------
// Kernel 2: out = sum_i soft[:,i] * (x_i @ W_tr_i + b_tr_i)
// BM=128, BN=128, BK=64, 256 threads (4 waves, 2M x 2N, wave 64x64).
// Same T3 pipeline; softmax weight folded into A at cvt (round-2 numerics).
// Grid (4 n-tiles fast, 128 m) so A-panel sharers dispatch adjacently.
// ---------------------------------------------------------------------------
__global__ __launch_bounds__(256, 2) void out_kernel(
    const float* __restrict__ x0, const float* __restrict__ x1, const float* __restrict__ x2,
    const float* __restrict__ bt0, const float* __restrict__ bt1, const float* __restrict__ bt2,
    const f16* __restrict__ wtt, const float* __restrict__ logits,
    float* __restrict__ out)
{
    __shared__ __align__(16) char sA[2][16384];   // 128 rows x 64 f16 (swz128)
    __shared__ __align__(16) char sB[2][16384];   // 128 rows x 64 f16 (swz128 via source)
    __shared__ float sS[128][4];

    int n0 = blockIdx.x * 128;
    int m0 = blockIdx.y * 128;
    int t = threadIdx.x;
    int l = t & 63;
    int w = t >> 6;
    int wm = w >> 1, wn = w & 1;
    int fr = l & 15;
    int ch = l >> 4;

    if (t < 128) {
        float l0 = logits[(size_t)(m0 + t) * 3 + 0];
        float l1 = logits[(size_t)(m0 + t) * 3 + 1];
        float l2 = logits[(size_t)(m0 + t) * 3 + 2];
        float mx = fmaxf(l0, fmaxf(l1, l2));
        float e0 = __expf(l0 - mx), e1 = __expf(l1 - mx), e2 = __expf(l2 - mx);
        float inv = 1.0f / (e0 + e1 + e2);
        sS[t][0] = e0 * inv; sS[t][1] = e1 * inv; sS[t][2] = e2 * inv;
    }
    __syncthreads();

    // A staging: thread t covers row=t>>1, k-half h=t&1 (32 f32 -> 32 f16)
    int s_row = t >> 1, s_h = t & 1;
    size_t xroff = (size_t)(m0 + s_row) * KDIM + s_h * 32;
    float sv0 = sS[s_row][0], sv1 = sS[s_row][1], sv2 = sS[s_row][2];
    int awb[4];
    #pragma unroll
    for (int j2 = 0; j2 < 4; ++j2) awb[j2] = swz128(s_row, s_h * 64 + j2 * 16);

    // B gld: 4 instrs/wave, each 8 rows x 128B = 1KB
    int gdst[4], gsrow[4], gsc[4];
    #pragma unroll
    for (int i2 = 0; i2 < 4; ++i2) {
        int nbase = w * 32 + i2 * 8;
        int o = nbase * 128 + l * 16;
        int row = o >> 7, within = o & 127;
        gdst[i2] = nbase * 128;
        gsrow[i2] = row;
        gsc[i2] = within ^ ((row & 7) << 4);
    }

    int aoff[4][2], boff[4][2];
    #pragma unroll
    for (int f = 0; f < 4; ++f)
        #pragma unroll
        for (int kk = 0; kk < 2; ++kk) {
            int row = wm * 64 + f * 16 + fr;
            int n   = wn * 64 + f * 16 + fr;
            aoff[f][kk] = swz128(row, (kk * 4 + ch) * 16);
            boff[f][kk] = swz128(n,   (kk * 4 + ch) * 16);
        }

    f32x4 acc[4][4];
    #pragma unroll
    for (int i = 0; i < 4; ++i)
        #pragma unroll
        for (int j = 0; j < 4; ++j) acc[i][j] = (f32x4)0.0f;

    // prologue: stage i=0 (brn=0, kt=0) into buf 0
    {
        const float* xp = x0 + xroff;
        float s = sv0;
        #pragma unroll
        for (int j2 = 0; j2 < 4; ++j2) {
            float4 a = *(const float4*)(xp + j2 * 8);
            float4 b = *(const float4*)(xp + j2 * 8 + 4);
            f16x8 hv;
            hv[0] = (f16)(a.x * s); hv[1] = (f16)(a.y * s); hv[2] = (f16)(a.z * s); hv[3] = (f16)(a.w * s);
            hv[4] = (f16)(b.x * s); hv[5] = (f16)(b.y * s); hv[6] = (f16)(b.z * s); hv[7] = (f16)(b.w * s);
            *(f16x8*)(sA[0] + awb[j2]) = hv;
        }
        const char* wb = (const char*)wtt;
        #pragma unroll
        for (int i2 = 0; i2 < 4; ++i2)
            gld16(sB[0] + gdst[i2], wb + (size_t)(n0 + gsrow[i2]) * 2048 + gsc[i2], l);
    }
    __syncthreads();

    int buf = 0;
    for (int i = 0; i < 48; ++i) {
        bool has = (i + 1) < 48;
        float4 av[8];
        int brn2 = (i + 1) >> 4;
        if (has) {
            int k0 = ((i + 1) & 15) * 64;
            const float* xp = sel3(brn2, x0, x1, x2) + xroff + k0;
            #pragma unroll
            for (int j = 0; j < 8; ++j) av[j] = *(const float4*)(xp + j * 4);
            const char* wb = (const char*)(wtt + (size_t)brn2 * ODIM * KDIM);
            #pragma unroll
            for (int i2 = 0; i2 < 4; ++i2)
                gld16(sB[buf ^ 1] + gdst[i2],
                      wb + (size_t)(n0 + gsrow[i2]) * 2048 + (size_t)k0 * 2 + gsc[i2], l);
        }
        // compute on buf
        f16x8 af[4][2], bf[4][2];
        #pragma unroll
        for (int f = 0; f < 4; ++f)
            #pragma unroll
            for (int kk = 0; kk < 2; ++kk) {
                af[f][kk] = *(const f16x8*)(sA[buf] + aoff[f][kk]);
                bf[f][kk] = *(const f16x8*)(sB[buf] + boff[f][kk]);
            }
        #pragma unroll
        for (int kk = 0; kk < 2; ++kk)
            #pragma unroll
            for (int fm = 0; fm < 4; ++fm)
                #pragma unroll
                for (int fn = 0; fn < 4; ++fn)
                    acc[fm][fn] = __builtin_amdgcn_mfma_f32_16x16x32_f16(
                        af[fm][kk], bf[fn][kk], acc[fm][fn], 0, 0, 0);
        if (has) {
            float s = (brn2 == 0) ? sv0 : (brn2 == 1) ? sv1 : sv2;
            #pragma unroll
            for (int j2 = 0; j2 < 4; ++j2) {
                float4 a = av[j2 * 2], b = av[j2 * 2 + 1];
                f16x8 hv;
                hv[0] = (f16)(a.x * s); hv[1] = (f16)(a.y * s); hv[2] = (f16)(a.z * s); hv[3] = (f16)(a.w * s);
                hv[4] = (f16)(b.x * s); hv[5] = (f16)(b.y * s); hv[6] = (f16)(b.z * s); hv[7] = (f16)(b.w * s);
                *(f16x8*)(sA[buf ^ 1] + awb[j2]) = hv;
            }
        }
        __syncthreads();
        buf ^= 1;
    }

    // ---- epilogue: + sum_i s_i * b_tr_i, fp32 store ----
    float btc[3][4];
    #pragma unroll
    for (int fn = 0; fn < 4; ++fn) {
        int col = n0 + wn * 64 + fn * 16 + fr;
        btc[0][fn] = bt0[col];
        btc[1][fn] = bt1[col];
        btc[2][fn] = bt2[col];
    }
    #pragma unroll
    for (int fm = 0; fm < 4; ++fm) {
        #pragma unroll
        for (int reg = 0; reg < 4; ++reg) {
            int row = wm * 64 + fm * 16 + ch * 4 + reg;
            float s0 = sS[row][0], s1 = sS[row][1], s2 = sS[row][2];
            #pragma unroll
            for (int fn = 0; fn < 4; ++fn) {
                int col = n0 + wn * 64 + fn * 16 + fr;
                float val = acc[fm][fn][reg]
                          + s0 * btc[0][fn] + s1 * btc[1][fn] + s2 * btc[2][fn];
                out[(size_t)(m0 + row) * ODIM + col] = val;
            }
        }
    }
}

// ---------------------------------------------------------------------------
extern "C" void kernel_launch(void* const* d_in, const int* in_sizes, int n_in,
                              void* d_out, int out_size, void* d_ws, size_t ws_size,
                              hipStream_t stream)
{
    (void)in_sizes; (void)n_in; (void)out_size; (void)ws_size;
    const float* x0  = (const float*)d_in[0];
    const float* Wa0 = (const float*)d_in[1];
    const float* ba0 = (const float*)d_in[2];
    const float* Wt0 = (const float*)d_in[3];
    const float* bt0 = (const float*)d_in[4];
    const float* x1  = (const float*)d_in[5];
    const float* Wa1 = (const float*)d_in[6];
    const float* ba1 = (const float*)d_in[7];
    const float* Wt1 = (const float*)d_in[8];
    const float* bt1 = (const float*)d_in[9];
    const float* x2  = (const float*)d_in[10];
    const float* Wa2 = (const float*)d_in[11];
    const float* ba2 = (const float*)d_in[12];
    const float* Wt2 = (const float*)d_in[13];
    const float* bt2 = (const float*)d_in[14];
    const float* v   = (const float*)d_in[15];

    char* ws = (char*)d_ws;
    float* logits = (float*)(ws + WS_LOGITS);
    f16* wta = (f16*)(ws + WS_WT_ATT);
    f16* wtt = (f16*)(ws + WS_WT_TR);
    float* out = (float*)d_out;

    transpose_w_kernel<<<dim3(128, 6), 256, 0, stream>>>(Wa0, Wa1, Wa2, Wt0, Wt1, Wt2, wta, wtt);
    logits_kernel<<<dim3(NROWS / 64, 3), 512, 0, stream>>>(x0, x1, x2, ba0, ba1, ba2, wta, v, logits);
    out_kernel<<<dim3(4, NROWS / 128), 256, 0, stream>>>(x0, x1, x2, bt0, bt1, bt2, wtt, logits, out);
}

// Round 7
// 355.148 us; speedup vs baseline: 1.6442x; 1.1424x over previous
//
#include <hip/hip_runtime.h>

typedef _Float16 f16;
typedef f16 f16x8 __attribute__((ext_vector_type(8)));
typedef float f32x4 __attribute__((ext_vector_type(4)));
typedef unsigned int u32;

#define NROWS 16384
#define KDIM  1024
#define IDIM  256
#define ODIM  512

// ---- workspace layout (bytes) ----
#define WS_WT_ATT 262144
#define WS_WT_TR  1835008

__device__ __forceinline__ float fast_tanhf(float x) {
    float ax = fabsf(x);
    float e = __expf(-2.0f * ax);
    float t = (1.0f - e) / (1.0f + e);
    return copysignf(t, x);
}

__device__ __forceinline__ const float* sel3(int i, const float* a, const float* b, const float* c) {
    return i == 0 ? a : (i == 1 ? b : c);
}

__device__ __forceinline__ f16x8 cvt8(float4 a, float4 b) {
    f16x8 r;
    r[0] = (f16)a.x; r[1] = (f16)a.y; r[2] = (f16)a.z; r[3] = (f16)a.w;
    r[4] = (f16)b.x; r[5] = (f16)b.y; r[6] = (f16)b.z; r[7] = (f16)b.w;
    return r;
}
__device__ __forceinline__ f16x8 cvt8s(float4 a, float4 b, float s) {
    f16x8 r;
    r[0] = (f16)(a.x * s); r[1] = (f16)(a.y * s); r[2] = (f16)(a.z * s); r[3] = (f16)(a.w * s);
    r[4] = (f16)(b.x * s); r[5] = (f16)(b.y * s); r[6] = (f16)(b.z * s); r[7] = (f16)(b.w * s);
    return r;
}

// async 16B/lane global->LDS; lds_base wave-uniform, global per-lane (G21)
__device__ __forceinline__ void gld16(char* lds_base, const char* g, int lane) {
#if __has_builtin(__builtin_amdgcn_global_load_lds)
    __builtin_amdgcn_global_load_lds((const __attribute__((address_space(1))) u32*)g,
                                     (__attribute__((address_space(3))) u32*)lds_base, 16, 0, 0);
#else
    *(f16x8*)(lds_base + lane * 16) = *(const f16x8*)g;
#endif
}

// 128B-row XOR swizzle (PASS-verified in round 5)
__device__ __forceinline__ int swz128(int row, int c) { return (row * 128 + c) ^ ((row & 7) << 4); }

// ---------------------------------------------------------------------------
// Kernel 0: transpose + f16-convert weights: W[K][N] -> WT[N][K]
// ---------------------------------------------------------------------------
__global__ __launch_bounds__(256) void transpose_w_kernel(
    const float* __restrict__ Wa0, const float* __restrict__ Wa1, const float* __restrict__ Wa2,
    const float* __restrict__ Wt0, const float* __restrict__ Wt1, const float* __restrict__ Wt2,
    f16* __restrict__ wta, f16* __restrict__ wtt)
{
    __shared__ float tile[64][65];
    int mat = blockIdx.y;
    const float* src;
    f16* dst;
    int N;
    if (mat < 3) {
        src = (mat == 0) ? Wa0 : (mat == 1) ? Wa1 : Wa2;
        dst = wta + (size_t)mat * IDIM * KDIM;
        N = IDIM;
    } else {
        int m = mat - 3;
        src = (m == 0) ? Wt0 : (m == 1) ? Wt1 : Wt2;
        dst = wtt + (size_t)m * ODIM * KDIM;
        N = ODIM;
    }
    int ntiles = (N / 64) * (KDIM / 64);
    int tilei = blockIdx.x;
    if (tilei >= ntiles) return;
    int tn = tilei / (KDIM / 64);
    int tk = tilei % (KDIM / 64);
    int n0 = tn * 64, k0 = tk * 64;
    int t = threadIdx.x;

    #pragma unroll
    for (int j = 0; j < 16; ++j) {
        int f = j * 256 + t;
        int r = f >> 6, c = f & 63;
        tile[r][c] = src[(size_t)(k0 + r) * N + n0 + c];
    }
    __syncthreads();
    #pragma unroll
    for (int j = 0; j < 8; ++j) {
        int p = j * 256 + t;
        int n = p >> 5, kp = p & 31;
        union { f16 h[2]; unsigned int u; } pk;
        pk.h[0] = (f16)tile[2 * kp][n];
        pk.h[1] = (f16)tile[2 * kp + 1][n];
        *(unsigned int*)(&dst[(size_t)(n0 + n) * KDIM + k0 + 2 * kp]) = pk.u;
    }
}

// ---------------------------------------------------------------------------
// Fused kernel: per 64-row block:
//   pass A: logits_br = tanh(x_br @ Wa_br + ba_br) @ v   (3 branches, K=1024)
//   softmax in LDS
//   pass B: out = sum_br s_br*(x_br @ Wt_br) + sum s_br*bt_br  (K=3x1024)
// x read from HBM once (pass A); pass B re-reads same panel from L2/L3.
// 512 threads = 8 waves (2M x 4N). BK=64, double-buffered, B via gld16 with
// pre-swizzled source (all pieces verbatim from round-5 PASSED kernels).
// ---------------------------------------------------------------------------
__global__ __launch_bounds__(512, 2) void fused_kernel(
    const float* __restrict__ x0, const float* __restrict__ x1, const float* __restrict__ x2,
    const float* __restrict__ ba0, const float* __restrict__ ba1, const float* __restrict__ ba2,
    const float* __restrict__ bt0, const float* __restrict__ bt1, const float* __restrict__ bt2,
    const f16* __restrict__ wta, const f16* __restrict__ wtt, const float* __restrict__ v,
    float* __restrict__ out)
{
    __shared__ __align__(16) char sA[2][8192];    // 64 rows x 64 f16, swz128
    __shared__ __align__(16) char sB[2][65536];   // up to 512 rows x 64 f16, swz128 (via source)
    __shared__ float red[256];
    __shared__ float lgs[64][3];
    __shared__ float sS[64][4];

    const int m0 = blockIdx.x * 64;
    const int t = threadIdx.x;
    const int l = t & 63;
    const int w = t >> 6;            // 0..7
    const int wm = w >> 2, wn = w & 3;
    const int fr = l & 15, ch = l >> 4;

    // A staging: thread t covers row=t>>3, 8 floats at cols (t&7)*8
    const int srow = t >> 3, sseg = t & 7;
    const int aw0 = swz128(srow, sseg * 16);
    const size_t xoff = (size_t)(m0 + srow) * KDIM + sseg * 8;

    // B gld lane constant: row-within-8 stride + pre-swizzled byte (round-5 math)
    const int laneB = (l >> 3) * (KDIM * 2) + (((l * 16) & 127) ^ (((l >> 3) & 7) << 4));

    // ---------------- pass A: logits ----------------
    for (int br = 0; br < 3; ++br) {
        const float* x = sel3(br, x0, x1, x2);
        const f16* WA = wta + (size_t)br * IDIM * KDIM;

        f32x4 accA[2][4];
        #pragma unroll
        for (int i = 0; i < 2; ++i)
            #pragma unroll
            for (int j = 0; j < 4; ++j) accA[i][j] = (f32x4)0.0f;

        // prologue: stage kt=0 into buf 0
        {
            const float* p = x + xoff;
            float4 a0 = *(const float4*)p, a1 = *(const float4*)(p + 4);
            *(f16x8*)(sA[0] + aw0) = cvt8(a0, a1);
            const char* srcb = (const char*)WA + laneB;
            #pragma unroll
            for (int i2 = 0; i2 < 4; ++i2) {
                int nbase = w * 32 + i2 * 8;
                gld16(sB[0] + nbase * 128, srcb + (size_t)nbase * (KDIM * 2), l);
            }
        }
        __syncthreads();

        int buf = 0;
        for (int kt = 0; kt < 16; ++kt) {
            bool has = (kt + 1) < 16;
            float4 a0, a1;
            if (has) {
                const float* p = x + xoff + (kt + 1) * 64;
                a0 = *(const float4*)p; a1 = *(const float4*)(p + 4);
                const char* srcb = (const char*)WA + (size_t)(kt + 1) * 128 + laneB;
                #pragma unroll
                for (int i2 = 0; i2 < 4; ++i2) {
                    int nbase = w * 32 + i2 * 8;
                    gld16(sB[buf ^ 1] + nbase * 128, srcb + (size_t)nbase * (KDIM * 2), l);
                }
            }
            #pragma unroll
            for (int kk = 0; kk < 2; ++kk) {
                f16x8 af[2], bf[4];
                #pragma unroll
                for (int fm = 0; fm < 2; ++fm)
                    af[fm] = *(const f16x8*)(sA[buf] + swz128(wm * 32 + fm * 16 + fr, (kk * 4 + ch) * 16));
                #pragma unroll
                for (int fn = 0; fn < 4; ++fn)
                    bf[fn] = *(const f16x8*)(sB[buf] + swz128(wn * 64 + fn * 16 + fr, (kk * 4 + ch) * 16));
                #pragma unroll
                for (int fm = 0; fm < 2; ++fm)
                    #pragma unroll
                    for (int fn = 0; fn < 4; ++fn)
                        accA[fm][fn] = __builtin_amdgcn_mfma_f32_16x16x32_f16(
                            af[fm], bf[fn], accA[fm][fn], 0, 0, 0);
            }
            if (has) *(f16x8*)(sA[buf ^ 1] + aw0) = cvt8(a0, a1);
            __syncthreads();
            buf ^= 1;
        }

        // epilogue: tanh(acc + ba) . v, reduce 256 cols (round-5 logits verbatim)
        const float* ba = sel3(br, ba0, ba1, ba2);
        float vv[4], bb[4];
        #pragma unroll
        for (int fn = 0; fn < 4; ++fn) {
            int col = wn * 64 + fn * 16 + fr;
            vv[fn] = v[col];
            bb[fn] = ba[col];
        }
        #pragma unroll
        for (int fm = 0; fm < 2; ++fm) {
            #pragma unroll
            for (int reg = 0; reg < 4; ++reg) {
                float s = 0.f;
                #pragma unroll
                for (int fn = 0; fn < 4; ++fn)
                    s += fast_tanhf(accA[fm][fn][reg] + bb[fn]) * vv[fn];
                #pragma unroll
                for (int d = 1; d < 16; d <<= 1)
                    s += __shfl_xor(s, d, 64);
                if (fr == 0) {
                    int row = wm * 32 + fm * 16 + ch * 4 + reg;
                    red[wn * 64 + row] = s;
                }
            }
        }
        __syncthreads();
        if (t < 64) lgs[t][br] = red[t] + red[64 + t] + red[128 + t] + red[192 + t];
        __syncthreads();
    }

    // ---------------- softmax ----------------
    if (t < 64) {
        float l0 = lgs[t][0], l1 = lgs[t][1], l2 = lgs[t][2];
        float mx = fmaxf(l0, fmaxf(l1, l2));
        float e0 = __expf(l0 - mx), e1 = __expf(l1 - mx), e2 = __expf(l2 - mx);
        float inv = 1.0f / (e0 + e1 + e2);
        sS[t][0] = e0 * inv; sS[t][1] = e1 * inv; sS[t][2] = e2 * inv;
    }
    __syncthreads();

    // ---------------- pass B: output GEMM ----------------
    const float sv0 = sS[srow][0], sv1 = sS[srow][1], sv2 = sS[srow][2];

    f32x4 accB[2][8];
    #pragma unroll
    for (int i = 0; i < 2; ++i)
        #pragma unroll
        for (int j = 0; j < 8; ++j) accB[i][j] = (f32x4)0.0f;

    // prologue: i=0 (br 0, kt 0) into buf 0
    {
        const float* p = x0 + xoff;
        float4 a0 = *(const float4*)p, a1 = *(const float4*)(p + 4);
        *(f16x8*)(sA[0] + aw0) = cvt8s(a0, a1, sv0);
        const char* srcb = (const char*)wtt + laneB;
        #pragma unroll
        for (int i2 = 0; i2 < 8; ++i2) {
            int nbase = w * 64 + i2 * 8;
            gld16(sB[0] + nbase * 128, srcb + (size_t)nbase * (KDIM * 2), l);
        }
    }
    __syncthreads();

    int buf = 0;
    for (int i = 0; i < 48; ++i) {
        bool has = (i + 1) < 48;
        int bn = (i + 1) >> 4, kn = (i + 1) & 15;
        float4 a0, a1;
        if (has) {
            const float* p = sel3(bn, x0, x1, x2) + xoff + kn * 64;
            a0 = *(const float4*)p; a1 = *(const float4*)(p + 4);
            const char* srcb = (const char*)(wtt + (size_t)bn * ODIM * KDIM) + (size_t)kn * 128 + laneB;
            #pragma unroll
            for (int i2 = 0; i2 < 8; ++i2) {
                int nbase = w * 64 + i2 * 8;
                gld16(sB[buf ^ 1] + nbase * 128, srcb + (size_t)nbase * (KDIM * 2), l);
            }
        }
        #pragma unroll
        for (int kk = 0; kk < 2; ++kk) {
            f16x8 af[2], bf[8];
            #pragma unroll
            for (int fm = 0; fm < 2; ++fm)
                af[fm] = *(const f16x8*)(sA[buf] + swz128(wm * 32 + fm * 16 + fr, (kk * 4 + ch) * 16));
            #pragma unroll
            for (int fn = 0; fn < 8; ++fn)
                bf[fn] = *(const f16x8*)(sB[buf] + swz128(wn * 128 + fn * 16 + fr, (kk * 4 + ch) * 16));
            #pragma unroll
            for (int fm = 0; fm < 2; ++fm)
                #pragma unroll
                for (int fn = 0; fn < 8; ++fn)
                    accB[fm][fn] = __builtin_amdgcn_mfma_f32_16x16x32_f16(
                        af[fm], bf[fn], accB[fm][fn], 0, 0, 0);
        }
        if (has) {
            float s = (bn == 0) ? sv0 : (bn == 1) ? sv1 : sv2;
            *(f16x8*)(sA[buf ^ 1] + aw0) = cvt8s(a0, a1, s);
        }
        __syncthreads();
        buf ^= 1;
    }

    // ---- store epilogue: + sum_i s_i * bt_i ----
    float btc[3][8];
    #pragma unroll
    for (int fn = 0; fn < 8; ++fn) {
        int col = wn * 128 + fn * 16 + fr;
        btc[0][fn] = bt0[col];
        btc[1][fn] = bt1[col];
        btc[2][fn] = bt2[col];
    }
    #pragma unroll
    for (int fm = 0; fm < 2; ++fm) {
        #pragma unroll
        for (int reg = 0; reg < 4; ++reg) {
            int row = wm * 32 + fm * 16 + ch * 4 + reg;
            float s0 = sS[row][0], s1 = sS[row][1], s2 = sS[row][2];
            #pragma unroll
            for (int fn = 0; fn < 8; ++fn) {
                int col = wn * 128 + fn * 16 + fr;
                out[(size_t)(m0 + row) * ODIM + col] = accB[fm][fn][reg]
                    + s0 * btc[0][fn] + s1 * btc[1][fn] + s2 * btc[2][fn];
            }
        }
    }
}

// ---------------------------------------------------------------------------
extern "C" void kernel_launch(void* const* d_in, const int* in_sizes, int n_in,
                              void* d_out, int out_size, void* d_ws, size_t ws_size,
                              hipStream_t stream)
{
    (void)in_sizes; (void)n_in; (void)out_size; (void)ws_size;
    const float* x0  = (const float*)d_in[0];
    const float* Wa0 = (const float*)d_in[1];
    const float* ba0 = (const float*)d_in[2];
    const float* Wt0 = (const float*)d_in[3];
    const float* bt0 = (const float*)d_in[4];
    const float* x1  = (const float*)d_in[5];
    const float* Wa1 = (const float*)d_in[6];
    const float* ba1 = (const float*)d_in[7];
    const float* Wt1 = (const float*)d_in[8];
    const float* bt1 = (const float*)d_in[9];
    const float* x2  = (const float*)d_in[10];
    const float* Wa2 = (const float*)d_in[11];
    const float* ba2 = (const float*)d_in[12];
    const float* Wt2 = (const float*)d_in[13];
    const float* bt2 = (const float*)d_in[14];
    const float* v   = (const float*)d_in[15];

    char* ws = (char*)d_ws;
    f16* wta = (f16*)(ws + WS_WT_ATT);
    f16* wtt = (f16*)(ws + WS_WT_TR);
    float* out = (float*)d_out;

    transpose_w_kernel<<<dim3(128, 6), 256, 0, stream>>>(Wa0, Wa1, Wa2, Wt0, Wt1, Wt2, wta, wtt);
    fused_kernel<<<dim3(NROWS / 64), 512, 0, stream>>>(x0, x1, x2, ba0, ba1, ba2,
                                                       bt0, bt1, bt2, wta, wtt, v, out);
}